// Round 1
// baseline (293.366 us; speedup 1.0000x reference)
//
#include <hip/hip_runtime.h>
#include <math.h>

// Problem constants (B=4, S=2048, D_MODEL=512, H=8, DQ=64)
#define BATCH 4
#define SEQ   2048
#define DM    512
#define NH    8
#define DQ    64
#define BS    (BATCH*SEQ)     // 8192 rows
#define APAD  72              // padded tile stride in gemms

// q pre-scale: 1/sqrt(64) * log2(e), so softmax uses native 2^x (v_exp_f32)
#define QSCALE 0.18033688011112042f

typedef short  short8   __attribute__((ext_vector_type(8)));
typedef float  floatx4  __attribute__((ext_vector_type(4)));
typedef float  floatx16 __attribute__((ext_vector_type(16)));
typedef unsigned short ushort8 __attribute__((ext_vector_type(8)));
typedef unsigned uintx2 __attribute__((ext_vector_type(2)));
typedef unsigned uintx4 __attribute__((ext_vector_type(4)));

// cheap bf16: round-half-up (1 add + shift). Ties-only delta vs RNE.
__device__ __forceinline__ unsigned short f2bf(float f) {
    return (unsigned short)((__float_as_uint(f) + 0x8000u) >> 16);
}
// pack two floats -> two bf16 in one u32 (lo = a, hi = b): 2 adds + 1 v_perm
__device__ __forceinline__ unsigned pack2bf(float a, float b) {
    unsigned ua = __float_as_uint(a) + 0x8000u;
    unsigned ub = __float_as_uint(b) + 0x8000u;
    return __builtin_amdgcn_perm(ub, ua, 0x07060302u);  // {ub[3],ub[2],ua[3],ua[2]}
}

// ---------------------------------------------------------------------------
// convert_w: pack weights to bf16 B^T layout [n][k].
//   which 0..2: wt[which][h*64+d][dd] = W[h][dd][d]  (qkv projections)
//   which 3:    wo[o][c] = Wout[o][c]                 (already B^T)
// grid (256, 4).
// ---------------------------------------------------------------------------
__global__ __launch_bounds__(256) void convert_w_kernel(
    const float* __restrict__ Wq, const float* __restrict__ Wk,
    const float* __restrict__ Wv, const float* __restrict__ Wo,
    unsigned short* __restrict__ wt, unsigned short* __restrict__ wo)
{
    const int which = blockIdx.y;
    const int idx = blockIdx.x * 256 + threadIdx.x;   // 65536 per matrix
    if (which == 3) {
        float4 v = *(const float4*)(Wo + (size_t)idx * 4);
        uint2 o;
        o.x = pack2bf(v.x, v.y);
        o.y = pack2bf(v.z, v.w);
        *(uint2*)(wo + (size_t)idx * 4) = o;
    } else {
        const float* W = (which == 0) ? Wq : (which == 1) ? Wk : Wv;
        const int n   = idx >> 7;          // 0..511  (h*64+d)
        const int dd0 = (idx & 127) * 4;
        const int h = n >> 6, d = n & 63;
        uint2 o;
        o.x = pack2bf(W[((size_t)h * DM + dd0 + 0) * DQ + d],
                      W[((size_t)h * DM + dd0 + 1) * DQ + d]);
        o.y = pack2bf(W[((size_t)h * DM + dd0 + 2) * DQ + d],
                      W[((size_t)h * DM + dd0 + 3) * DQ + d]);
        *(uint2*)(wt + (size_t)which * (DM * DM) + (size_t)n * DM + dd0) = o;
    }
}

// ---------------------------------------------------------------------------
// qkv GEMM: 128x128 tile, BK=64, K=512 (8 k-steps). A (fp32 x, packed to
// bf16 at store) and B (bf16 weights) register-prefetched across the barrier.
// Outputs: which 0 -> q*QSCALE bf16 [b,h,s,d]; 1 -> k bf16 [b,h,s,d];
//          2 -> v bf16 [b,h,d,s].
// grid (64, 4, 3), block 256.
// ---------------------------------------------------------------------------
__global__ __launch_bounds__(256) void qkv_gemm_kernel(
    const float* __restrict__ Xq, const float* __restrict__ Xk,
    const float* __restrict__ Xv, const unsigned short* __restrict__ wt,
    unsigned short* __restrict__ Oq, unsigned short* __restrict__ Ok,
    unsigned short* __restrict__ Ovt)
{
    __shared__ unsigned short As[128][APAD];
    __shared__ unsigned short Bs[128][APAD];

    const int which = blockIdx.z;
    const float* X = (which == 0) ? Xq : (which == 1) ? Xk : Xv;
    const unsigned short* Bt = wt + (size_t)which * (DM * DM);

    const int m0 = blockIdx.x * 128;
    const int n0 = blockIdx.y * 128;
    const int t = threadIdx.x, w = t >> 6, lane = t & 63;
    const int quad = lane >> 4, qr = lane & 15;
    const int arow = t >> 4;           // A staging: 16 rows/pass
    const int acol = (t & 15) * 4;     // float4 col
    const int brow = t >> 3;           // B staging: 32 rows/pass
    const int bcol = (t & 7) * 8;      // ushort8 col
    const int mw = 64 * (w >> 1), nw = 64 * (w & 1);

    floatx4 acc[4][4] = {};
    float4  areg[8];
    ushort8 breg[4];

    #pragma unroll
    for (int i = 0; i < 8; ++i)
        areg[i] = *(const float4*)(X + (size_t)(m0 + i * 16 + arow) * DM + acol);
    #pragma unroll
    for (int i = 0; i < 4; ++i)
        breg[i] = *(const ushort8*)(Bt + (size_t)(n0 + i * 32 + brow) * DM + bcol);

    for (int k0 = 0; k0 < DM; k0 += 64) {
        __syncthreads();
        #pragma unroll
        for (int i = 0; i < 8; ++i) {
            uint2 o;
            o.x = pack2bf(areg[i].x, areg[i].y);
            o.y = pack2bf(areg[i].z, areg[i].w);
            *(uint2*)&As[i * 16 + arow][acol] = o;
        }
        #pragma unroll
        for (int i = 0; i < 4; ++i)
            *(ushort8*)&Bs[i * 32 + brow][bcol] = breg[i];
        __syncthreads();

        if (k0 + 64 < DM) {
            #pragma unroll
            for (int i = 0; i < 8; ++i)
                areg[i] = *(const float4*)(X + (size_t)(m0 + i * 16 + arow) * DM + k0 + 64 + acol);
            #pragma unroll
            for (int i = 0; i < 4; ++i)
                breg[i] = *(const ushort8*)(Bt + (size_t)(n0 + i * 32 + brow) * DM + k0 + 64 + bcol);
        }

        #pragma unroll
        for (int kh = 0; kh < 2; ++kh) {
            short8 af[4], bf[4];
            #pragma unroll
            for (int si = 0; si < 4; ++si)
                af[si] = *(const short8*)&As[mw + 16 * si + qr][kh * 32 + quad * 8];
            #pragma unroll
            for (int sj = 0; sj < 4; ++sj)
                bf[sj] = *(const short8*)&Bs[nw + 16 * sj + qr][kh * 32 + quad * 8];
            #pragma unroll
            for (int si = 0; si < 4; ++si)
                #pragma unroll
                for (int sj = 0; sj < 4; ++sj)
                    acc[si][sj] = __builtin_amdgcn_mfma_f32_16x16x32_bf16(
                        af[si], bf[sj], acc[si][sj], 0, 0, 0);
        }
    }

    const float osc = (which == 0) ? QSCALE : 1.0f;
    if (which < 2) {
        unsigned short* O = (which == 0) ? Oq : Ok;
        #pragma unroll
        for (int si = 0; si < 4; ++si) {
            #pragma unroll
            for (int sj = 0; sj < 4; ++sj) {
                const int col = n0 + nw + 16 * sj + qr;
                const int h = col >> 6, d = col & 63;
                #pragma unroll
                for (int r = 0; r < 4; ++r) {
                    const int row = m0 + mw + 16 * si + quad * 4 + r;
                    const int b = row >> 11, s = row & (SEQ - 1);
                    O[((size_t)(b * NH + h) * SEQ + s) * DQ + d] = f2bf(acc[si][sj][r] * osc);
                }
            }
        }
    } else {
        #pragma unroll
        for (int si = 0; si < 4; ++si) {
            #pragma unroll
            for (int sj = 0; sj < 4; ++sj) {
                const int col = n0 + nw + 16 * sj + qr;
                const int h = col >> 6, d = col & 63;
                #pragma unroll
                for (int r = 0; r < 4; ++r) {
                    const int row = m0 + mw + 16 * si + quad * 4 + r;
                    const int b = row >> 11, s = row & (SEQ - 1);
                    Ovt[((size_t)(b * NH + h) * DQ + d) * SEQ + s] = f2bf(acc[si][sj][r]);
                }
            }
        }
    }
}

// ---------------------------------------------------------------------------
// out GEMM: 64x128 tile (512 blocks = 2/CU), BK=64, register-prefetched.
// ---------------------------------------------------------------------------
__global__ __launch_bounds__(256) void out_gemm_kernel(
    const unsigned short* __restrict__ A, const unsigned short* __restrict__ Bt,
    float* __restrict__ C)
{
    __shared__ unsigned short As[64][APAD];
    __shared__ unsigned short Bs[128][APAD];

    const int m0 = blockIdx.x * 64;
    const int n0 = blockIdx.y * 128;
    const int t = threadIdx.x, w = t >> 6, lane = t & 63;
    const int quad = lane >> 4, qr = lane & 15;
    const int brow = t >> 3;           // 32 rows/pass
    const int bcol = (t & 7) * 8;
    const int mw = 32 * (w >> 1), nw = 64 * (w & 1);

    floatx4 acc[2][4] = {};
    ushort8 areg[2], breg[4];

    #pragma unroll
    for (int i = 0; i < 2; ++i)
        areg[i] = *(const ushort8*)(A + (size_t)(m0 + i * 32 + brow) * DM + bcol);
    #pragma unroll
    for (int i = 0; i < 4; ++i)
        breg[i] = *(const ushort8*)(Bt + (size_t)(n0 + i * 32 + brow) * DM + bcol);

    for (int k0 = 0; k0 < DM; k0 += 64) {
        __syncthreads();
        #pragma unroll
        for (int i = 0; i < 2; ++i)
            *(ushort8*)&As[i * 32 + brow][bcol] = areg[i];
        #pragma unroll
        for (int i = 0; i < 4; ++i)
            *(ushort8*)&Bs[i * 32 + brow][bcol] = breg[i];
        __syncthreads();

        if (k0 + 64 < DM) {
            #pragma unroll
            for (int i = 0; i < 2; ++i)
                areg[i] = *(const ushort8*)(A + (size_t)(m0 + i * 32 + brow) * DM + k0 + 64 + bcol);
            #pragma unroll
            for (int i = 0; i < 4; ++i)
                breg[i] = *(const ushort8*)(Bt + (size_t)(n0 + i * 32 + brow) * DM + k0 + 64 + bcol);
        }

        #pragma unroll
        for (int kh = 0; kh < 2; ++kh) {
            short8 af[2], bf[4];
            #pragma unroll
            for (int si = 0; si < 2; ++si)
                af[si] = *(const short8*)&As[mw + 16 * si + qr][kh * 32 + quad * 8];
            #pragma unroll
            for (int sj = 0; sj < 4; ++sj)
                bf[sj] = *(const short8*)&Bs[nw + 16 * sj + qr][kh * 32 + quad * 8];
            #pragma unroll
            for (int si = 0; si < 2; ++si)
                #pragma unroll
                for (int sj = 0; sj < 4; ++sj)
                    acc[si][sj] = __builtin_amdgcn_mfma_f32_16x16x32_bf16(
                        af[si], bf[sj], acc[si][sj], 0, 0, 0);
        }
    }

    #pragma unroll
    for (int si = 0; si < 2; ++si) {
        #pragma unroll
        for (int sj = 0; sj < 4; ++sj) {
            const int col = n0 + nw + 16 * sj + qr;
            #pragma unroll
            for (int r = 0; r < 4; ++r) {
                const int row = m0 + mw + 16 * si + quad * 4 + r;
                C[(size_t)row * DM + col] = acc[si][sj][r];
            }
        }
    }
}

// ---------------------------------------------------------------------------
// flash attention v7: changes vs v6 (59.2 us, MfmaUtil 23%, 2.1M LDS
// bank-conflict cycles, 68 MB FETCH vs 24 MB ideal):
//  - T12: P round-trip through LDS (Ps quadrant, the 4-way-conflicting b64
//    writes = the whole conflict counter) replaced by 4x permlane32_swap.
//    Lane l and l^32 jointly hold exactly the PV A-fragment words:
//    swap(w[g][i], w[g+1][i]) -> ret0 = [A_g | A_g+1] (word kv-lo),
//    ret1 = [B_g | B_g+1] (word kv-hi). LDS ops/wave-iter 18 -> 12.
//  - LDS 36.8 KB -> 24 KB (Ps dropped, BPAD 72 -> 64 with XOR swizzle
//    col8 ^ ((row&7)*8) on both LDS write and read; reg-staged so legal;
//    quarter-wave frag reads stay <=2-way = free) -> 6 blocks/CU.
//  - T1: bijective XCD swizzle (flat grid 1024 = 8 XCDs x 4 bh x 32 tiles):
//    all 32 q-tile blocks of one (b,h) land on one XCD -> K/V working set
//    2 MB per 4 MB L2 (was 16 MB -> thrash).
//  - T5: s_setprio(1) around both MFMA clusters.
// Epilogue combine aliases Obuf (64x66 f32) over dead Q/K/V tiles, lbuf at
// the smem tail. grid = (1024), block 256.
// MFMA 32x32x16 layouts: A[m=lane&31][k=(lane>>5)*8+j],
// B[k=(lane>>5)*8+j][n=lane&31], C/D col=lane&31,
// row=(reg&3)+8*(reg>>2)+4*(lane>>5)  (HW-verified m74/m101).
// ---------------------------------------------------------------------------
__global__ __launch_bounds__(256, 6) void attn_kernel(
    const unsigned short* __restrict__ Qp, const unsigned short* __restrict__ Kp,
    const unsigned short* __restrict__ Vtp, unsigned short* __restrict__ Hd)
{
    __shared__ unsigned short smem[3 * 64 * 64];   // 24 KB: Qs, Ks, Vts
    unsigned short (*Qs)[64]  = (unsigned short (*)[64])(smem);
    unsigned short (*Ks)[64]  = (unsigned short (*)[64])(smem + 64 * 64);
    unsigned short (*Vts)[64] = (unsigned short (*)[64])(smem + 2 * 64 * 64);

    // XCD-aware decode: xcd = f&7 (round-robin dispatch), each XCD owns
    // 4 complete bh-groups (1024 % 8 == 0 -> bijective).
    const int f    = blockIdx.x;
    const int xcd  = f & 7;
    const int slot = f >> 3;            // 0..127 within XCD
    const int tile = slot & 31;         // q-tile
    const int bhi  = (slot >> 5) * 8 + xcd;   // 0..31
    const int b = bhi >> 3, h = bhi & 7;

    const int s0 = tile * 64;
    const size_t bh    = (size_t)(b * NH + h);
    const size_t base  = bh * SEQ * DQ;       // [b,h,s,d]
    const size_t vbase = bh * DQ * SEQ;       // [b,h,d,s]

    const int t    = threadIdx.x;
    const int w    = t >> 6;
    const int lane = t & 63;
    const int qh   = w >> 1;      // q-half (rows 32qh..32qh+31)
    const int kh   = w & 1;       // kv-half within each 64-kv tile
    const int ln31 = lane & 31;
    const int lh   = lane >> 5;   // lane half

    // ---- stage Q tile (XOR-swizzled) ----
    {
        const unsigned short* g = Qp + base + (size_t)s0 * DQ;
        #pragma unroll
        for (int i = 0; i < 2; ++i) {
            const int c = t + 256 * i;
            const int row = c >> 3, col8 = (c & 7) * 8;
            *(ushort8*)&Qs[row][col8 ^ ((row & 7) * 8)] = *(const ushort8*)(g + row * DQ + col8);
        }
    }
    __syncthreads();
    // hoist Q B-fragments: B[k=d][n=q], q = 32qh + ln31
    short8 bq[4];
    {
        const int qrow = 32 * qh + ln31;
        #pragma unroll
        for (int s = 0; s < 4; ++s)
            bq[s] = *(const short8*)&Qs[qrow][(16 * s + lh * 8) ^ ((qrow & 7) * 8)];
    }

    floatx16 accO[2] = {};   // partial O[32q][64dv]: a=dv-block; lane col=dv
    float l_lane = 0.f;

    // ---- prefetch first K/V tile into registers ----
    ushort8 kreg[2], vreg[2];
    {
        const unsigned short* gk = Kp + base;
        const unsigned short* gv = Vtp + vbase;
        #pragma unroll
        for (int i = 0; i < 2; ++i) {
            const int c = t + 256 * i;
            const int row = c >> 3, col8 = (c & 7) * 8;
            kreg[i] = *(const ushort8*)(gk + row * DQ + col8);
            vreg[i] = *(const ushort8*)(gv + (size_t)row * SEQ + col8);
        }
    }

    for (int kt = 0; kt < SEQ; kt += 64) {
        __syncthreads();   // prev iteration's reads of Ks/Vts complete
        #pragma unroll
        for (int i = 0; i < 2; ++i) {
            const int c = t + 256 * i;
            const int row = c >> 3, col8 = (c & 7) * 8;
            const int sc = col8 ^ ((row & 7) * 8);
            *(ushort8*)&Ks[row][sc]  = kreg[i];
            *(ushort8*)&Vts[row][sc] = vreg[i];
        }
        __syncthreads();

        if (kt + 64 < SEQ) {
            const unsigned short* gk = Kp + base + (size_t)(kt + 64) * DQ;
            const unsigned short* gv = Vtp + vbase + (kt + 64);
            #pragma unroll
            for (int i = 0; i < 2; ++i) {
                const int c = t + 256 * i;
                const int row = c >> 3, col8 = (c & 7) * 8;
                kreg[i] = *(const ushort8*)(gk + row * DQ + col8);
                vreg[i] = *(const ushort8*)(gv + (size_t)row * SEQ + col8);
            }
        }

        // ---- S^T[32kv][32q] = K-half @ Q-half^T (4-chain over d=64) ----
        floatx16 z = {};
        __builtin_amdgcn_s_setprio(1);
        {
            const int krow = 32 * kh + ln31;
            #pragma unroll
            for (int s = 0; s < 4; ++s) {
                const short8 ak = *(const short8*)&Ks[krow][(16 * s + lh * 8) ^ ((krow & 7) * 8)];
                z = __builtin_amdgcn_mfma_f32_32x32x16_bf16(ak, bq[s], z, 0, 0, 0);
            }
        }
        __builtin_amdgcn_s_setprio(0);

        // ---- exp2, l accumulate, pack P (reg 4g+j -> kv = 8g+4lh+j) ----
        unsigned wg[4][2];
        #pragma unroll
        for (int g = 0; g < 4; ++g) {
            const float p0 = __builtin_amdgcn_exp2f(z[4 * g + 0]);
            const float p1 = __builtin_amdgcn_exp2f(z[4 * g + 1]);
            const float p2 = __builtin_amdgcn_exp2f(z[4 * g + 2]);
            const float p3 = __builtin_amdgcn_exp2f(z[4 * g + 3]);
            l_lane += (p0 + p1) + (p2 + p3);
            wg[g][0] = pack2bf(p0, p1);
            wg[g][1] = pack2bf(p2, p3);
        }

        // ---- T12: build PV A-fragments in-register via permlane32_swap ----
        // reg w[g][i]: lanes<32 hold kv pairs (8g+2i, 8g+2i+1)          [= A_g_i]
        //              lanes>=32 hold kv pairs (8g+4+2i, 8g+4+2i+1)     [= B_g_i]
        // swap(a,b) -> ret0 = [a_lo|b_lo], ret1 = [a_hi|b_hi]:
        //   ap0 = { [A0|A1]_0, [A0|A1]_1, [B0|B1]_0, [B0|B1]_1 }  (kv 8lh..8lh+7 etc.)
        const uintx2 e0 = __builtin_amdgcn_permlane32_swap(wg[0][0], wg[1][0], false, false);
        const uintx2 e1 = __builtin_amdgcn_permlane32_swap(wg[0][1], wg[1][1], false, false);
        const uintx2 e2 = __builtin_amdgcn_permlane32_swap(wg[2][0], wg[3][0], false, false);
        const uintx2 e3 = __builtin_amdgcn_permlane32_swap(wg[2][1], wg[3][1], false, false);
        uintx4 ua0, ua1;
        ua0[0] = e0[0]; ua0[1] = e1[0]; ua0[2] = e0[1]; ua0[3] = e1[1];
        ua1[0] = e2[0]; ua1[1] = e3[0]; ua1[2] = e2[1]; ua1[3] = e3[1];
        const short8 ap0 = __builtin_bit_cast(short8, ua0);
        const short8 ap1 = __builtin_bit_cast(short8, ua1);

        // ---- PV: accO[a] += P[32q][32kv] @ V[32kv][32dv] ----
        __builtin_amdgcn_s_setprio(1);
        #pragma unroll
        for (int a = 0; a < 2; ++a) {
            const int vrow = 32 * a + ln31;
            #pragma unroll
            for (int s = 0; s < 2; ++s) {
                const short8 bv = *(const short8*)&Vts[vrow][(32 * kh + 16 * s + lh * 8) ^ ((vrow & 7) * 8)];
                accO[a] = __builtin_amdgcn_mfma_f32_32x32x16_bf16(
                    (s == 0) ? ap0 : ap1, bv, accO[a], 0, 0, 0);
            }
        }
        __builtin_amdgcn_s_setprio(0);
    }

    // ---- cross-kh combine: O and l, via LDS aliased over dead Q/K/V ----
    float l2 = l_lane + __shfl_xor(l_lane, 32);   // full kv-half sum for q=32qh+ln31
    float* Obuf = (float*)smem;                        // 64x66 f32 = 16.9 KB
    float* lbuf = (float*)(smem + 3 * 64 * 64 - 256);  // 512 B tail: [0..63] kh0-l, [64..127] inv_l
    __syncthreads();                                   // all LDS reads of the loop done

    if (kh == 0) {
        if (lane < 32) lbuf[qh * 32 + lane] = l2;
        #pragma unroll
        for (int a = 0; a < 2; ++a)
            #pragma unroll
            for (int r = 0; r < 16; ++r) {
                const int qrow = (r & 3) + 8 * (r >> 2) + 4 * lh;
                Obuf[(32 * qh + qrow) * 66 + 32 * a + ln31] = accO[a][r];
            }
    }
    __syncthreads();

    if (kh == 1) {
        const float ltot = l2 + lbuf[qh * 32 + ln31];
        if (lane < 32) lbuf[64 + qh * 32 + lane] = 1.0f / ltot;  // same-wave RAW
        #pragma unroll
        for (int a = 0; a < 2; ++a)
            #pragma unroll
            for (int r = 0; r < 16; ++r) {
                const int qrow = (r & 3) + 8 * (r >> 2) + 4 * lh;
                const float o = accO[a][r] + Obuf[(32 * qh + qrow) * 66 + 32 * a + ln31];
                const float iv = lbuf[64 + qh * 32 + qrow];
                Hd[base + (size_t)(s0 + 32 * qh + qrow) * DQ + 32 * a + ln31] = f2bf(o * iv);
            }
    }
}

// ---------------------------------------------------------------------------
// kernel_launch
// Workspace (ushort units):
//   wt:    0        (3 x 262144)    qkv weights bf16, B^T [h*64+d][dd]
//   wo:    786432   (262144)        Wout bf16 [o][c]
//   q_ws:  1048576  (4194304)       q*QSCALE bf16 [b,h,s,d]
//   k_ws:  5242880  (4194304)       k bf16 [b,h,s,d]
//   vt_ws: 9437184  (4194304)       v bf16 [b,h,d,s]
//   h_ws:  13631488 (4194304)       heads bf16 (flat GEMM-A view)
// total ~34 MB
// ---------------------------------------------------------------------------
extern "C" void kernel_launch(void* const* d_in, const int* in_sizes, int n_in,
                              void* d_out, int out_size, void* d_ws, size_t ws_size,
                              hipStream_t stream) {
    const float* xq = (const float*)d_in[0];
    const float* xk = (const float*)d_in[1];
    const float* xv = (const float*)d_in[2];
    const float* Qw = (const float*)d_in[3];
    const float* Kw = (const float*)d_in[4];
    const float* Vw = (const float*)d_in[5];
    const float* Wo = (const float*)d_in[6];
    float* out = (float*)d_out;

    unsigned short* ws = (unsigned short*)d_ws;
    unsigned short* wt    = ws;
    unsigned short* wo    = ws + (size_t)786432;
    unsigned short* q_ws  = ws + (size_t)1048576;
    unsigned short* k_ws  = ws + (size_t)5242880;
    unsigned short* vt_ws = ws + (size_t)9437184;
    unsigned short* h_ws  = ws + (size_t)13631488;

    convert_w_kernel<<<dim3(256, 4), 256, 0, stream>>>(Qw, Kw, Vw, Wo, wt, wo);
    qkv_gemm_kernel<<<dim3(64, 4, 3), 256, 0, stream>>>(xq, xk, xv, wt, q_ws, k_ws, vt_ws);
    attn_kernel<<<dim3(1024), 256, 0, stream>>>(q_ws, k_ws, vt_ws, h_ws);
    out_gemm_kernel<<<dim3(128, 4), 256, 0, stream>>>(h_ws, wo, out);
}

// Round 2
// 185.559 us; speedup vs baseline: 1.5810x; 1.5810x over previous
//
#include <hip/hip_runtime.h>
#include <math.h>

// Problem constants (B=4, S=2048, D_MODEL=512, H=8, DQ=64)
#define BATCH 4
#define SEQ   2048
#define DM    512
#define NH    8
#define DQ    64
#define BS    (BATCH*SEQ)     // 8192 rows
#define APAD  72              // padded tile stride in gemms

// q pre-scale: 1/sqrt(64) * log2(e), so softmax uses native 2^x (v_exp_f32)
#define QSCALE 0.18033688011112042f

typedef short  short8   __attribute__((ext_vector_type(8)));
typedef float  floatx4  __attribute__((ext_vector_type(4)));
typedef float  floatx16 __attribute__((ext_vector_type(16)));
typedef unsigned short ushort8 __attribute__((ext_vector_type(8)));
typedef unsigned uintx2 __attribute__((ext_vector_type(2)));
typedef unsigned uintx4 __attribute__((ext_vector_type(4)));

// cheap bf16: round-half-up (1 add + shift). Ties-only delta vs RNE.
__device__ __forceinline__ unsigned short f2bf(float f) {
    return (unsigned short)((__float_as_uint(f) + 0x8000u) >> 16);
}
// pack two floats -> two bf16 in one u32 (lo = a, hi = b): 2 adds + 1 v_perm
__device__ __forceinline__ unsigned pack2bf(float a, float b) {
    unsigned ua = __float_as_uint(a) + 0x8000u;
    unsigned ub = __float_as_uint(b) + 0x8000u;
    return __builtin_amdgcn_perm(ub, ua, 0x07060302u);  // {ub[3],ub[2],ua[3],ua[2]}
}

// ---------------------------------------------------------------------------
// convert_w: pack weights to bf16 B^T layout [n][k].
//   which 0..2: wt[which][h*64+d][dd] = W[h][dd][d]  (qkv projections)
//   which 3:    wo[o][c] = Wout[o][c]                 (already B^T)
// grid (256, 4).
// ---------------------------------------------------------------------------
__global__ __launch_bounds__(256) void convert_w_kernel(
    const float* __restrict__ Wq, const float* __restrict__ Wk,
    const float* __restrict__ Wv, const float* __restrict__ Wo,
    unsigned short* __restrict__ wt, unsigned short* __restrict__ wo)
{
    const int which = blockIdx.y;
    const int idx = blockIdx.x * 256 + threadIdx.x;   // 65536 per matrix
    if (which == 3) {
        float4 v = *(const float4*)(Wo + (size_t)idx * 4);
        uint2 o;
        o.x = pack2bf(v.x, v.y);
        o.y = pack2bf(v.z, v.w);
        *(uint2*)(wo + (size_t)idx * 4) = o;
    } else {
        const float* W = (which == 0) ? Wq : (which == 1) ? Wk : Wv;
        const int n   = idx >> 7;          // 0..511  (h*64+d)
        const int dd0 = (idx & 127) * 4;
        const int h = n >> 6, d = n & 63;
        uint2 o;
        o.x = pack2bf(W[((size_t)h * DM + dd0 + 0) * DQ + d],
                      W[((size_t)h * DM + dd0 + 1) * DQ + d]);
        o.y = pack2bf(W[((size_t)h * DM + dd0 + 2) * DQ + d],
                      W[((size_t)h * DM + dd0 + 3) * DQ + d]);
        *(uint2*)(wt + (size_t)which * (DM * DM) + (size_t)n * DM + dd0) = o;
    }
}

// ---------------------------------------------------------------------------
// qkv GEMM: 128x128 tile, BK=64, K=512 (8 k-steps). A (fp32 x, packed to
// bf16 at store) and B (bf16 weights) register-prefetched across the barrier.
// Outputs: which 0 -> q*QSCALE bf16 [b,h,s,d]; 1 -> k bf16 [b,h,s,d];
//          2 -> v bf16 [b,h,d,s].
// grid (64, 4, 3), block 256.
// ---------------------------------------------------------------------------
__global__ __launch_bounds__(256) void qkv_gemm_kernel(
    const float* __restrict__ Xq, const float* __restrict__ Xk,
    const float* __restrict__ Xv, const unsigned short* __restrict__ wt,
    unsigned short* __restrict__ Oq, unsigned short* __restrict__ Ok,
    unsigned short* __restrict__ Ovt)
{
    __shared__ unsigned short As[128][APAD];
    __shared__ unsigned short Bs[128][APAD];

    const int which = blockIdx.z;
    const float* X = (which == 0) ? Xq : (which == 1) ? Xk : Xv;
    const unsigned short* Bt = wt + (size_t)which * (DM * DM);

    const int m0 = blockIdx.x * 128;
    const int n0 = blockIdx.y * 128;
    const int t = threadIdx.x, w = t >> 6, lane = t & 63;
    const int quad = lane >> 4, qr = lane & 15;
    const int arow = t >> 4;           // A staging: 16 rows/pass
    const int acol = (t & 15) * 4;     // float4 col
    const int brow = t >> 3;           // B staging: 32 rows/pass
    const int bcol = (t & 7) * 8;      // ushort8 col
    const int mw = 64 * (w >> 1), nw = 64 * (w & 1);

    floatx4 acc[4][4] = {};
    float4  areg[8];
    ushort8 breg[4];

    #pragma unroll
    for (int i = 0; i < 8; ++i)
        areg[i] = *(const float4*)(X + (size_t)(m0 + i * 16 + arow) * DM + acol);
    #pragma unroll
    for (int i = 0; i < 4; ++i)
        breg[i] = *(const ushort8*)(Bt + (size_t)(n0 + i * 32 + brow) * DM + bcol);

    for (int k0 = 0; k0 < DM; k0 += 64) {
        __syncthreads();
        #pragma unroll
        for (int i = 0; i < 8; ++i) {
            uint2 o;
            o.x = pack2bf(areg[i].x, areg[i].y);
            o.y = pack2bf(areg[i].z, areg[i].w);
            *(uint2*)&As[i * 16 + arow][acol] = o;
        }
        #pragma unroll
        for (int i = 0; i < 4; ++i)
            *(ushort8*)&Bs[i * 32 + brow][bcol] = breg[i];
        __syncthreads();

        if (k0 + 64 < DM) {
            #pragma unroll
            for (int i = 0; i < 8; ++i)
                areg[i] = *(const float4*)(X + (size_t)(m0 + i * 16 + arow) * DM + k0 + 64 + acol);
            #pragma unroll
            for (int i = 0; i < 4; ++i)
                breg[i] = *(const ushort8*)(Bt + (size_t)(n0 + i * 32 + brow) * DM + k0 + 64 + bcol);
        }

        #pragma unroll
        for (int kh = 0; kh < 2; ++kh) {
            short8 af[4], bf[4];
            #pragma unroll
            for (int si = 0; si < 4; ++si)
                af[si] = *(const short8*)&As[mw + 16 * si + qr][kh * 32 + quad * 8];
            #pragma unroll
            for (int sj = 0; sj < 4; ++sj)
                bf[sj] = *(const short8*)&Bs[nw + 16 * sj + qr][kh * 32 + quad * 8];
            #pragma unroll
            for (int si = 0; si < 4; ++si)
                #pragma unroll
                for (int sj = 0; sj < 4; ++sj)
                    acc[si][sj] = __builtin_amdgcn_mfma_f32_16x16x32_bf16(
                        af[si], bf[sj], acc[si][sj], 0, 0, 0);
        }
    }

    const float osc = (which == 0) ? QSCALE : 1.0f;
    if (which < 2) {
        unsigned short* O = (which == 0) ? Oq : Ok;
        #pragma unroll
        for (int si = 0; si < 4; ++si) {
            #pragma unroll
            for (int sj = 0; sj < 4; ++sj) {
                const int col = n0 + nw + 16 * sj + qr;
                const int h = col >> 6, d = col & 63;
                #pragma unroll
                for (int r = 0; r < 4; ++r) {
                    const int row = m0 + mw + 16 * si + quad * 4 + r;
                    const int b = row >> 11, s = row & (SEQ - 1);
                    O[((size_t)(b * NH + h) * SEQ + s) * DQ + d] = f2bf(acc[si][sj][r] * osc);
                }
            }
        }
    } else {
        #pragma unroll
        for (int si = 0; si < 4; ++si) {
            #pragma unroll
            for (int sj = 0; sj < 4; ++sj) {
                const int col = n0 + nw + 16 * sj + qr;
                const int h = col >> 6, d = col & 63;
                #pragma unroll
                for (int r = 0; r < 4; ++r) {
                    const int row = m0 + mw + 16 * si + quad * 4 + r;
                    const int b = row >> 11, s = row & (SEQ - 1);
                    Ovt[((size_t)(b * NH + h) * DQ + d) * SEQ + s] = f2bf(acc[si][sj][r]);
                }
            }
        }
    }
}

// ---------------------------------------------------------------------------
// out GEMM: 64x128 tile (512 blocks = 2/CU), BK=64, register-prefetched.
// ---------------------------------------------------------------------------
__global__ __launch_bounds__(256) void out_gemm_kernel(
    const unsigned short* __restrict__ A, const unsigned short* __restrict__ Bt,
    float* __restrict__ C)
{
    __shared__ unsigned short As[64][APAD];
    __shared__ unsigned short Bs[128][APAD];

    const int m0 = blockIdx.x * 64;
    const int n0 = blockIdx.y * 128;
    const int t = threadIdx.x, w = t >> 6, lane = t & 63;
    const int quad = lane >> 4, qr = lane & 15;
    const int brow = t >> 3;           // 32 rows/pass
    const int bcol = (t & 7) * 8;
    const int mw = 32 * (w >> 1), nw = 64 * (w & 1);

    floatx4 acc[2][4] = {};
    ushort8 areg[2], breg[4];

    #pragma unroll
    for (int i = 0; i < 2; ++i)
        areg[i] = *(const ushort8*)(A + (size_t)(m0 + i * 32 + brow) * DM + bcol);
    #pragma unroll
    for (int i = 0; i < 4; ++i)
        breg[i] = *(const ushort8*)(Bt + (size_t)(n0 + i * 32 + brow) * DM + bcol);

    for (int k0 = 0; k0 < DM; k0 += 64) {
        __syncthreads();
        #pragma unroll
        for (int i = 0; i < 2; ++i)
            *(ushort8*)&As[i * 32 + brow][bcol] = areg[i];
        #pragma unroll
        for (int i = 0; i < 4; ++i)
            *(ushort8*)&Bs[i * 32 + brow][bcol] = breg[i];
        __syncthreads();

        if (k0 + 64 < DM) {
            #pragma unroll
            for (int i = 0; i < 2; ++i)
                areg[i] = *(const ushort8*)(A + (size_t)(m0 + i * 32 + brow) * DM + k0 + 64 + bcol);
            #pragma unroll
            for (int i = 0; i < 4; ++i)
                breg[i] = *(const ushort8*)(Bt + (size_t)(n0 + i * 32 + brow) * DM + k0 + 64 + bcol);
        }

        #pragma unroll
        for (int kh = 0; kh < 2; ++kh) {
            short8 af[2], bf[4];
            #pragma unroll
            for (int si = 0; si < 2; ++si)
                af[si] = *(const short8*)&As[mw + 16 * si + qr][kh * 32 + quad * 8];
            #pragma unroll
            for (int sj = 0; sj < 4; ++sj)
                bf[sj] = *(const short8*)&Bs[nw + 16 * sj + qr][kh * 32 + quad * 8];
            #pragma unroll
            for (int si = 0; si < 2; ++si)
                #pragma unroll
                for (int sj = 0; sj < 4; ++sj)
                    acc[si][sj] = __builtin_amdgcn_mfma_f32_16x16x32_bf16(
                        af[si], bf[sj], acc[si][sj], 0, 0, 0);
        }
    }

    #pragma unroll
    for (int si = 0; si < 2; ++si) {
        #pragma unroll
        for (int sj = 0; sj < 4; ++sj) {
            const int col = n0 + nw + 16 * sj + qr;
            #pragma unroll
            for (int r = 0; r < 4; ++r) {
                const int row = m0 + mw + 16 * si + quad * 4 + r;
                C[(size_t)row * DM + col] = acc[si][sj][r];
            }
        }
    }
}

// ---------------------------------------------------------------------------
// flash attention v8 = v7 with the spill fixed.
// v7 post-mortem: __launch_bounds__(256,6) capped the VGPR budget below the
// ~100 regs of live state (accO 32 + bq 16 + kreg/vreg 16 + permlane temps);
// compiler spilled accumulators to scratch -> WRITE_SIZE 8 MB -> 267 MB,
// MfmaUtil 23% -> 8%, dur 59 -> 172 us. Revert to (256, 4) (128-VGPR class,
// v6's setting). Kept from v7 (all verified-correct, absmax unchanged):
//  - T12: P round-trip via 4x permlane32_swap instead of LDS Ps quadrant
//    (LDS ops/wave-iter 18 -> 12, Ps buffer freed).
//  - LDS 36.8 KB -> 24 KB (BPAD 72 -> 64 with XOR swizzle col8^((row&7)*8)
//    on both LDS write and read; reg-staged so legal; frag reads <=2-way).
//  - T1: bijective XCD swizzle (1024 = 8 XCDs x 4 bh x 32 tiles): all 32
//    q-tile blocks of one (b,h) on one XCD -> K/V set 2 MB per 4 MB L2.
//  - T5: s_setprio(1) around both MFMA clusters.
// grid = (1024), block 256.
// MFMA 32x32x16 layouts: A[m=lane&31][k=(lane>>5)*8+j],
// B[k=(lane>>5)*8+j][n=lane&31], C/D col=lane&31,
// row=(reg&3)+8*(reg>>2)+4*(lane>>5)  (HW-verified m74/m101).
// ---------------------------------------------------------------------------
__global__ __launch_bounds__(256, 4) void attn_kernel(
    const unsigned short* __restrict__ Qp, const unsigned short* __restrict__ Kp,
    const unsigned short* __restrict__ Vtp, unsigned short* __restrict__ Hd)
{
    __shared__ unsigned short smem[3 * 64 * 64];   // 24 KB: Qs, Ks, Vts
    unsigned short (*Qs)[64]  = (unsigned short (*)[64])(smem);
    unsigned short (*Ks)[64]  = (unsigned short (*)[64])(smem + 64 * 64);
    unsigned short (*Vts)[64] = (unsigned short (*)[64])(smem + 2 * 64 * 64);

    // XCD-aware decode: xcd = f&7 (round-robin dispatch), each XCD owns
    // 4 complete bh-groups (1024 % 8 == 0 -> bijective).
    const int f    = blockIdx.x;
    const int xcd  = f & 7;
    const int slot = f >> 3;            // 0..127 within XCD
    const int tile = slot & 31;         // q-tile
    const int bhi  = (slot >> 5) * 8 + xcd;   // 0..31
    const int b = bhi >> 3, h = bhi & 7;

    const int s0 = tile * 64;
    const size_t bh    = (size_t)(b * NH + h);
    const size_t base  = bh * SEQ * DQ;       // [b,h,s,d]
    const size_t vbase = bh * DQ * SEQ;       // [b,h,d,s]

    const int t    = threadIdx.x;
    const int w    = t >> 6;
    const int lane = t & 63;
    const int qh   = w >> 1;      // q-half (rows 32qh..32qh+31)
    const int kh   = w & 1;       // kv-half within each 64-kv tile
    const int ln31 = lane & 31;
    const int lh   = lane >> 5;   // lane half

    // ---- stage Q tile (XOR-swizzled) ----
    {
        const unsigned short* g = Qp + base + (size_t)s0 * DQ;
        #pragma unroll
        for (int i = 0; i < 2; ++i) {
            const int c = t + 256 * i;
            const int row = c >> 3, col8 = (c & 7) * 8;
            *(ushort8*)&Qs[row][col8 ^ ((row & 7) * 8)] = *(const ushort8*)(g + row * DQ + col8);
        }
    }
    __syncthreads();
    // hoist Q B-fragments: B[k=d][n=q], q = 32qh + ln31
    short8 bq[4];
    {
        const int qrow = 32 * qh + ln31;
        #pragma unroll
        for (int s = 0; s < 4; ++s)
            bq[s] = *(const short8*)&Qs[qrow][(16 * s + lh * 8) ^ ((qrow & 7) * 8)];
    }

    floatx16 accO[2] = {};   // partial O[32q][64dv]: a=dv-block; lane col=dv
    float l_lane = 0.f;

    // ---- prefetch first K/V tile into registers ----
    ushort8 kreg[2], vreg[2];
    {
        const unsigned short* gk = Kp + base;
        const unsigned short* gv = Vtp + vbase;
        #pragma unroll
        for (int i = 0; i < 2; ++i) {
            const int c = t + 256 * i;
            const int row = c >> 3, col8 = (c & 7) * 8;
            kreg[i] = *(const ushort8*)(gk + row * DQ + col8);
            vreg[i] = *(const ushort8*)(gv + (size_t)row * SEQ + col8);
        }
    }

    for (int kt = 0; kt < SEQ; kt += 64) {
        __syncthreads();   // prev iteration's reads of Ks/Vts complete
        #pragma unroll
        for (int i = 0; i < 2; ++i) {
            const int c = t + 256 * i;
            const int row = c >> 3, col8 = (c & 7) * 8;
            const int sc = col8 ^ ((row & 7) * 8);
            *(ushort8*)&Ks[row][sc]  = kreg[i];
            *(ushort8*)&Vts[row][sc] = vreg[i];
        }
        __syncthreads();

        if (kt + 64 < SEQ) {
            const unsigned short* gk = Kp + base + (size_t)(kt + 64) * DQ;
            const unsigned short* gv = Vtp + vbase + (kt + 64);
            #pragma unroll
            for (int i = 0; i < 2; ++i) {
                const int c = t + 256 * i;
                const int row = c >> 3, col8 = (c & 7) * 8;
                kreg[i] = *(const ushort8*)(gk + row * DQ + col8);
                vreg[i] = *(const ushort8*)(gv + (size_t)row * SEQ + col8);
            }
        }

        // ---- S^T[32kv][32q] = K-half @ Q-half^T (4-chain over d=64) ----
        floatx16 z = {};
        __builtin_amdgcn_s_setprio(1);
        {
            const int krow = 32 * kh + ln31;
            #pragma unroll
            for (int s = 0; s < 4; ++s) {
                const short8 ak = *(const short8*)&Ks[krow][(16 * s + lh * 8) ^ ((krow & 7) * 8)];
                z = __builtin_amdgcn_mfma_f32_32x32x16_bf16(ak, bq[s], z, 0, 0, 0);
            }
        }
        __builtin_amdgcn_s_setprio(0);

        // ---- exp2, l accumulate, pack P (reg 4g+j -> kv = 8g+4lh+j) ----
        unsigned wg[4][2];
        #pragma unroll
        for (int g = 0; g < 4; ++g) {
            const float p0 = __builtin_amdgcn_exp2f(z[4 * g + 0]);
            const float p1 = __builtin_amdgcn_exp2f(z[4 * g + 1]);
            const float p2 = __builtin_amdgcn_exp2f(z[4 * g + 2]);
            const float p3 = __builtin_amdgcn_exp2f(z[4 * g + 3]);
            l_lane += (p0 + p1) + (p2 + p3);
            wg[g][0] = pack2bf(p0, p1);
            wg[g][1] = pack2bf(p2, p3);
        }

        // ---- T12: build PV A-fragments in-register via permlane32_swap ----
        // reg w[g][i]: lanes<32 hold kv pairs (8g+2i, 8g+2i+1)          [= A_g_i]
        //              lanes>=32 hold kv pairs (8g+4+2i, 8g+4+2i+1)     [= B_g_i]
        // swap(a,b) -> ret0 = [a_lo|b_lo], ret1 = [a_hi|b_hi]:
        //   ap0 = { [A0|A1]_0, [A0|A1]_1, [B0|B1]_0, [B0|B1]_1 }  (kv 8lh..8lh+7 etc.)
        const uintx2 e0 = __builtin_amdgcn_permlane32_swap(wg[0][0], wg[1][0], false, false);
        const uintx2 e1 = __builtin_amdgcn_permlane32_swap(wg[0][1], wg[1][1], false, false);
        const uintx2 e2 = __builtin_amdgcn_permlane32_swap(wg[2][0], wg[3][0], false, false);
        const uintx2 e3 = __builtin_amdgcn_permlane32_swap(wg[2][1], wg[3][1], false, false);
        uintx4 ua0, ua1;
        ua0[0] = e0[0]; ua0[1] = e1[0]; ua0[2] = e0[1]; ua0[3] = e1[1];
        ua1[0] = e2[0]; ua1[1] = e3[0]; ua1[2] = e2[1]; ua1[3] = e3[1];
        const short8 ap0 = __builtin_bit_cast(short8, ua0);
        const short8 ap1 = __builtin_bit_cast(short8, ua1);

        // ---- PV: accO[a] += P[32q][32kv] @ V[32kv][32dv] ----
        __builtin_amdgcn_s_setprio(1);
        #pragma unroll
        for (int a = 0; a < 2; ++a) {
            const int vrow = 32 * a + ln31;
            #pragma unroll
            for (int s = 0; s < 2; ++s) {
                const short8 bv = *(const short8*)&Vts[vrow][(32 * kh + 16 * s + lh * 8) ^ ((vrow & 7) * 8)];
                accO[a] = __builtin_amdgcn_mfma_f32_32x32x16_bf16(
                    (s == 0) ? ap0 : ap1, bv, accO[a], 0, 0, 0);
            }
        }
        __builtin_amdgcn_s_setprio(0);
    }

    // ---- cross-kh combine: O and l, via LDS aliased over dead Q/K/V ----
    float l2 = l_lane + __shfl_xor(l_lane, 32);   // full kv-half sum for q=32qh+ln31
    float* Obuf = (float*)smem;                        // 64x66 f32 = 16.9 KB
    float* lbuf = (float*)(smem + 3 * 64 * 64 - 256);  // 512 B tail: [0..63] kh0-l, [64..127] inv_l
    __syncthreads();                                   // all LDS reads of the loop done

    if (kh == 0) {
        if (lane < 32) lbuf[qh * 32 + lane] = l2;
        #pragma unroll
        for (int a = 0; a < 2; ++a)
            #pragma unroll
            for (int r = 0; r < 16; ++r) {
                const int qrow = (r & 3) + 8 * (r >> 2) + 4 * lh;
                Obuf[(32 * qh + qrow) * 66 + 32 * a + ln31] = accO[a][r];
            }
    }
    __syncthreads();

    if (kh == 1) {
        const float ltot = l2 + lbuf[qh * 32 + ln31];
        if (lane < 32) lbuf[64 + qh * 32 + lane] = 1.0f / ltot;  // same-wave RAW
        #pragma unroll
        for (int a = 0; a < 2; ++a)
            #pragma unroll
            for (int r = 0; r < 16; ++r) {
                const int qrow = (r & 3) + 8 * (r >> 2) + 4 * lh;
                const float o = accO[a][r] + Obuf[(32 * qh + qrow) * 66 + 32 * a + ln31];
                const float iv = lbuf[64 + qh * 32 + qrow];
                Hd[base + (size_t)(s0 + 32 * qh + qrow) * DQ + 32 * a + ln31] = f2bf(o * iv);
            }
    }
}

// ---------------------------------------------------------------------------
// kernel_launch
// Workspace (ushort units):
//   wt:    0        (3 x 262144)    qkv weights bf16, B^T [h*64+d][dd]
//   wo:    786432   (262144)        Wout bf16 [o][c]
//   q_ws:  1048576  (4194304)       q*QSCALE bf16 [b,h,s,d]
//   k_ws:  5242880  (4194304)       k bf16 [b,h,s,d]
//   vt_ws: 9437184  (4194304)       v bf16 [b,h,d,s]
//   h_ws:  13631488 (4194304)       heads bf16 (flat GEMM-A view)
// total ~34 MB
// ---------------------------------------------------------------------------
extern "C" void kernel_launch(void* const* d_in, const int* in_sizes, int n_in,
                              void* d_out, int out_size, void* d_ws, size_t ws_size,
                              hipStream_t stream) {
    const float* xq = (const float*)d_in[0];
    const float* xk = (const float*)d_in[1];
    const float* xv = (const float*)d_in[2];
    const float* Qw = (const float*)d_in[3];
    const float* Kw = (const float*)d_in[4];
    const float* Vw = (const float*)d_in[5];
    const float* Wo = (const float*)d_in[6];
    float* out = (float*)d_out;

    unsigned short* ws = (unsigned short*)d_ws;
    unsigned short* wt    = ws;
    unsigned short* wo    = ws + (size_t)786432;
    unsigned short* q_ws  = ws + (size_t)1048576;
    unsigned short* k_ws  = ws + (size_t)5242880;
    unsigned short* vt_ws = ws + (size_t)9437184;
    unsigned short* h_ws  = ws + (size_t)13631488;

    convert_w_kernel<<<dim3(256, 4), 256, 0, stream>>>(Qw, Kw, Vw, Wo, wt, wo);
    qkv_gemm_kernel<<<dim3(64, 4, 3), 256, 0, stream>>>(xq, xk, xv, wt, q_ws, k_ws, vt_ws);
    attn_kernel<<<dim3(1024), 256, 0, stream>>>(q_ws, k_ws, vt_ws, h_ws);
    out_gemm_kernel<<<dim3(128, 4), 256, 0, stream>>>(h_ws, wo, out);
}